// Round 9
// baseline (1320.169 us; speedup 1.0000x reference)
//
#include <hip/hip_runtime.h>
#include <hip/hip_bf16.h>

// N=16384 queries, C=1024 classes, D=4096.
// sims = l2norm(hvs) @ l2norm(am)^T ; preds = argmax ; eta = (sims[:,1]-sims[:,0])/4 + 0.5
// R9: gemm1 restructured for co-residency: 256x128 tile, 48 KB LDS (dbuf BK=32)
// -> 3 blocks/CU; cross-block overlap hides LDS-read bursts under MFMA.
// norm_split merged into one launch. Pass-2 recheck unchanged from R8.

#define NQ 16384
#define NC 1024
#define DK 4096
#define TAU 4e-4f
#define WLMAX 8192

typedef __attribute__((ext_vector_type(8))) short short8;
typedef __attribute__((ext_vector_type(4))) float f32x4;
typedef unsigned short ushort_t;

__device__ __forceinline__ unsigned short bf16_rne(float x) {
    unsigned int u = __float_as_uint(x);
    u += 0x7FFFu + ((u >> 16) & 1u);
    return (unsigned short)(u >> 16);
}
__device__ __forceinline__ float bf16_f32(unsigned short h) {
    return __uint_as_float(((unsigned int)h) << 16);
}

#define GLDS(g, l)                                                                       \
    __builtin_amdgcn_global_load_lds((const __attribute__((address_space(1))) void*)(g), \
                                     (__attribute__((address_space(3))) void*)(l), 16, 0, 0)

// ---------------- fused row-norm + normalize + bf16 hi(/lo) split, both inputs ----------------
__global__ void __launch_bounds__(256) norm_all_kernel(const float* __restrict__ hvs,
                                                       const float* __restrict__ am,
                                                       ushort_t* __restrict__ Ah,
                                                       ushort_t* __restrict__ Bh,
                                                       ushort_t* __restrict__ Bl) {
    const int b = blockIdx.x;
    const int tid = threadIdx.x;
    const float* x;
    ushort_t *hp, *lp;
    bool wlo;
    if (b < NC) {
        x = am + (size_t)b * DK;
        hp = Bh + (size_t)b * DK;
        lp = Bl + (size_t)b * DK;
        wlo = true;
    } else {
        const int r = b - NC;
        x = hvs + (size_t)r * DK;
        hp = Ah + (size_t)r * DK;
        lp = nullptr;
        wlo = false;
    }
    const float4* x4 = (const float4*)x;

    float4 v[4];
    float ss = 0.f;
#pragma unroll
    for (int i = 0; i < 4; ++i) {
        v[i] = x4[tid * 4 + i];
        ss += v[i].x * v[i].x + v[i].y * v[i].y + v[i].z * v[i].z + v[i].w * v[i].w;
    }
#pragma unroll
    for (int off = 32; off; off >>= 1) ss += __shfl_xor(ss, off, 64);
    __shared__ float wsum[4];
    const int lane = tid & 63, w = tid >> 6;
    if (lane == 0) wsum[w] = ss;
    __syncthreads();
    const float tot = wsum[0] + wsum[1] + wsum[2] + wsum[3];
    const float r = 1.0f / fmaxf(sqrtf(tot), 1e-8f);

    ushort_t hbuf[16], lbuf[16];
#pragma unroll
    for (int i = 0; i < 4; ++i) {
        const float xs[4] = {v[i].x * r, v[i].y * r, v[i].z * r, v[i].w * r};
#pragma unroll
        for (int j = 0; j < 4; ++j) {
            const unsigned short h = bf16_rne(xs[j]);
            hbuf[i * 4 + j] = h;
            lbuf[i * 4 + j] = bf16_rne(xs[j] - bf16_f32(h));
        }
    }
    ushort_t* hq = hp + tid * 16;
    *(short8*)hq = *(short8*)hbuf;
    *(short8*)(hq + 8) = *(short8*)(hbuf + 8);
    if (wlo) {
        ushort_t* lq = lp + tid * 16;
        *(short8*)lq = *(short8*)lbuf;
        *(short8*)(lq + 8) = *(short8*)(lbuf + 8);
    }
}

// ---------------- pass 1: 1-term bf16 GEMM, 256x128 tile, 3 blocks/CU ----------------
// 8 waves (4M x 2N, each 64x64). dbuf LDS 48 KB. Issue-early stage + counted
// vmcnt(3), R3-proven 2-barrier skeleton + setprio MFMA cluster.
__global__ void __launch_bounds__(512, 6) gemm1_kernel(const ushort_t* __restrict__ Ah,
                                                       const ushort_t* __restrict__ Bh,
                                                       float4* __restrict__ cand,
                                                       float* __restrict__ s01) {
    __shared__ __align__(16) ushort_t lA[2][256 * 32];  // 32 KB
    __shared__ __align__(16) ushort_t lB[2][128 * 32];  // 16 KB

    const int tid = threadIdx.x;
    const int lane = tid & 63;
    const int w = tid >> 6;   // 0..7
    const int wm = w >> 1;    // 0..3 (64-row strip)
    const int wn = w & 1;     // 0..1 (64-col strip)

    // XCD swizzle: the 8 bx-blocks sharing a by-panel land on one XCD
    const int id = blockIdx.x;             // 0..511
    const int xcd = id & 7;
    const int slot = id >> 3;              // 0..63
    const int by = xcd * 8 + (slot >> 3);  // 0..63
    const int bx = slot & 7;               // 0..7

    // staging: A half = 256 rows x 4 slots(16B) = 1024 chunks (2/thread);
    //          B half = 128 rows x 4 slots = 512 chunks (1/thread). 3 GLDS/thread.
    int sqA[2];
    size_t offA[2];
#pragma unroll
    for (int i = 0; i < 2; ++i) {
        const int q = tid + i * 512;
        sqA[i] = q;
        const int row = q >> 2;
        const int gs = (q & 3) ^ ((row >> 1) & 3);
        offA[i] = (size_t)(by * 256 + row) * DK + gs * 8;
    }
    const int rowB = tid >> 2;
    const int gsB = (tid & 3) ^ ((rowB >> 1) & 3);
    const size_t offB = (size_t)(bx * 128 + rowB) * DK + gsB * 8;

    f32x4 acc[4][4];
#pragma unroll
    for (int m = 0; m < 4; ++m)
#pragma unroll
        for (int n = 0; n < 4; ++n) acc[m][n] = (f32x4){0.f, 0.f, 0.f, 0.f};

    const int r0 = lane & 15;
    const int rg = lane >> 4;

    int aoff[4], boff[4];
#pragma unroll
    for (int m = 0; m < 4; ++m) {
        const int row = wm * 64 + m * 16 + r0;
        aoff[m] = row * 32 + (rg ^ ((row >> 1) & 3)) * 8;
    }
#pragma unroll
    for (int n = 0; n < 4; ++n) {
        const int col = wn * 64 + n * 16 + r0;
        boff[n] = col * 32 + (rg ^ ((col >> 1) & 3)) * 8;
    }

    auto stage = [&](int buf, int kt) {
        const size_t ko = (size_t)kt * 32;
        GLDS(Ah + offA[0] + ko, &lA[buf][sqA[0] * 8]);
        GLDS(Ah + offA[1] + ko, &lA[buf][sqA[1] * 8]);
        GLDS(Bh + offB + ko, &lB[buf][tid * 8]);
    };

    stage(0, 0);
    const int nK = DK / 32;  // 128
    for (int kt = 0; kt < nK; ++kt) {
        const int cur = kt & 1;
        if (kt + 1 < nK) {
            stage(cur ^ 1, kt + 1);                           // 3 new loads in flight
            asm volatile("s_waitcnt vmcnt(3)" ::: "memory");  // cur's 3 done
        } else {
            asm volatile("s_waitcnt vmcnt(0)" ::: "memory");
        }
        __builtin_amdgcn_s_barrier();

        short8 b0 = *(const short8*)&lB[cur][boff[0]];
        short8 b1 = *(const short8*)&lB[cur][boff[1]];
        short8 b2 = *(const short8*)&lB[cur][boff[2]];
        short8 b3 = *(const short8*)&lB[cur][boff[3]];
        short8 a0 = *(const short8*)&lA[cur][aoff[0]];
        short8 a1 = *(const short8*)&lA[cur][aoff[1]];
        short8 a2 = *(const short8*)&lA[cur][aoff[2]];
        short8 a3 = *(const short8*)&lA[cur][aoff[3]];
        asm volatile("s_waitcnt lgkmcnt(0)" ::: "memory");
        __builtin_amdgcn_s_setprio(1);
        acc[0][0] = __builtin_amdgcn_mfma_f32_16x16x32_bf16(a0, b0, acc[0][0], 0, 0, 0);
        acc[0][1] = __builtin_amdgcn_mfma_f32_16x16x32_bf16(a0, b1, acc[0][1], 0, 0, 0);
        acc[0][2] = __builtin_amdgcn_mfma_f32_16x16x32_bf16(a0, b2, acc[0][2], 0, 0, 0);
        acc[0][3] = __builtin_amdgcn_mfma_f32_16x16x32_bf16(a0, b3, acc[0][3], 0, 0, 0);
        acc[1][0] = __builtin_amdgcn_mfma_f32_16x16x32_bf16(a1, b0, acc[1][0], 0, 0, 0);
        acc[1][1] = __builtin_amdgcn_mfma_f32_16x16x32_bf16(a1, b1, acc[1][1], 0, 0, 0);
        acc[1][2] = __builtin_amdgcn_mfma_f32_16x16x32_bf16(a1, b2, acc[1][2], 0, 0, 0);
        acc[1][3] = __builtin_amdgcn_mfma_f32_16x16x32_bf16(a1, b3, acc[1][3], 0, 0, 0);
        acc[2][0] = __builtin_amdgcn_mfma_f32_16x16x32_bf16(a2, b0, acc[2][0], 0, 0, 0);
        acc[2][1] = __builtin_amdgcn_mfma_f32_16x16x32_bf16(a2, b1, acc[2][1], 0, 0, 0);
        acc[2][2] = __builtin_amdgcn_mfma_f32_16x16x32_bf16(a2, b2, acc[2][2], 0, 0, 0);
        acc[2][3] = __builtin_amdgcn_mfma_f32_16x16x32_bf16(a2, b3, acc[2][3], 0, 0, 0);
        acc[3][0] = __builtin_amdgcn_mfma_f32_16x16x32_bf16(a3, b0, acc[3][0], 0, 0, 0);
        acc[3][1] = __builtin_amdgcn_mfma_f32_16x16x32_bf16(a3, b1, acc[3][1], 0, 0, 0);
        acc[3][2] = __builtin_amdgcn_mfma_f32_16x16x32_bf16(a3, b2, acc[3][2], 0, 0, 0);
        acc[3][3] = __builtin_amdgcn_mfma_f32_16x16x32_bf16(a3, b3, acc[3][3], 0, 0, 0);
        __builtin_amdgcn_s_setprio(0);
        __builtin_amdgcn_s_barrier();
    }

    // epilogue: C/D layout col=lane&15, row=(lane>>4)*4+j [m89]; per-strip top-2.
    // 16 col-strips of 64: strip index = bx*2 + wn (ascending col order).
    const int rowb = by * 256 + wm * 64;
#pragma unroll
    for (int m = 0; m < 4; ++m) {
#pragma unroll
        for (int j = 0; j < 4; ++j) {
            float v1 = acc[m][0][j];
            int i1 = bx * 128 + wn * 64 + r0;
            float v2 = -3.402823466e+38f;
#pragma unroll
            for (int n = 1; n < 4; ++n) {
                const float v = acc[m][n][j];
                const int c = bx * 128 + wn * 64 + n * 16 + r0;
                if (v > v1) { v2 = v1; v1 = v; i1 = c; }
                else { v2 = fmaxf(v2, v); }
            }
#pragma unroll
            for (int off = 1; off < 16; off <<= 1) {
                const float o1 = __shfl_xor(v1, off, 64);
                const int oi = __shfl_xor(i1, off, 64);
                const float o2 = __shfl_xor(v2, off, 64);
                if (o1 > v1 || (o1 == v1 && oi < i1)) { v2 = fmaxf(v1, o2); v1 = o1; i1 = oi; }
                else { v2 = fmaxf(v2, o1); }
            }
            const int row = rowb + m * 16 + rg * 4 + j;
            if (r0 == 0)
                cand[(size_t)row * 16 + bx * 2 + wn] = make_float4(v1, (float)i1, v2, 0.f);
            if (bx == 0 && wn == 0 && r0 < 2) s01[row * 2 + r0] = acc[m][0][j];
        }
    }
}

// ---------------- finalize pass 1: merge strips, flag close rows ----------------
__global__ void __launch_bounds__(256) finalizeA_kernel(const float4* __restrict__ cand,
                                                        const float* __restrict__ s01,
                                                        float* __restrict__ out,
                                                        int* __restrict__ wl,
                                                        int* __restrict__ wc) {
    const int row = blockIdx.x * 256 + threadIdx.x;
    const float4* c = cand + (size_t)row * 16;
    float4 c0 = c[0];
    float M = c0.x, iM = c0.y, M2 = c0.z;
#pragma unroll
    for (int k = 1; k < 16; ++k) {
        const float4 ck = c[k];
        if (ck.x > M) { M2 = fmaxf(M, ck.z); M = ck.x; iM = ck.y; }
        else { M2 = fmaxf(M2, ck.x); }
    }
    out[row] = iM;
    out[NQ + row] = (s01[row * 2 + 1] - s01[row * 2 + 0]) * 0.25f + 0.5f;
    if (M - M2 < TAU) {
        const int p = atomicAdd(wc, 1);
        if (p < WLMAX) wl[p] = row;
    }
}

// ---------------- recheck prep: gather flagged rows, normalize + hi/lo split ----------------
__global__ void __launch_bounds__(256) recheck_prep_kernel(const float* __restrict__ hvs,
                                                           const int* __restrict__ wl,
                                                           const int* __restrict__ wc,
                                                           ushort_t* __restrict__ A2h,
                                                           ushort_t* __restrict__ A2l) {
    const int cnt = min(*wc, WLMAX);
    const int s = blockIdx.x;
    if (s >= cnt) return;
    const int row = wl[s];
    const int tid = threadIdx.x;
    const float4* x4 = (const float4*)(hvs + (size_t)row * DK);

    float4 v[4];
    float ss = 0.f;
#pragma unroll
    for (int i = 0; i < 4; ++i) {
        v[i] = x4[tid * 4 + i];
        ss += v[i].x * v[i].x + v[i].y * v[i].y + v[i].z * v[i].z + v[i].w * v[i].w;
    }
#pragma unroll
    for (int off = 32; off; off >>= 1) ss += __shfl_xor(ss, off, 64);
    __shared__ float wsum[4];
    const int lane = tid & 63, w = tid >> 6;
    if (lane == 0) wsum[w] = ss;
    __syncthreads();
    const float tot = wsum[0] + wsum[1] + wsum[2] + wsum[3];
    const float r = 1.0f / fmaxf(sqrtf(tot), 1e-8f);

    ushort_t hbuf[16], lbuf[16];
#pragma unroll
    for (int i = 0; i < 4; ++i) {
        const float xs[4] = {v[i].x * r, v[i].y * r, v[i].z * r, v[i].w * r};
#pragma unroll
        for (int j = 0; j < 4; ++j) {
            const unsigned short h = bf16_rne(xs[j]);
            hbuf[i * 4 + j] = h;
            lbuf[i * 4 + j] = bf16_rne(xs[j] - bf16_f32(h));
        }
    }
    ushort_t* hp = A2h + (size_t)s * DK + tid * 16;
    ushort_t* lp = A2l + (size_t)s * DK + tid * 16;
    *(short8*)hp = *(short8*)hbuf;
    *(short8*)(hp + 8) = *(short8*)(hbuf + 8);
    *(short8*)lp = *(short8*)lbuf;
    *(short8*)(lp + 8) = *(short8*)(lbuf + 8);
}

// ---------------- pass 2: 3-term recheck, 128x128 blocks, 4-deep ring ----------------
// (unchanged from R8)
__global__ void __launch_bounds__(512, 2) gemm2_kernel(const ushort_t* __restrict__ A2h,
                                                       const ushort_t* __restrict__ A2l,
                                                       const ushort_t* __restrict__ Bh,
                                                       const ushort_t* __restrict__ Bl,
                                                       const int* __restrict__ wc,
                                                       float2* __restrict__ cand2) {
    const int cnt = min(*wc, WLMAX);
    const int by = blockIdx.y;
    const int bx = blockIdx.x;
    if (by * 128 >= cnt) return;

    __shared__ __align__(16) ushort_t lA[4][2][128 * 32];  // 64 KB
    __shared__ __align__(16) ushort_t lB[4][2][128 * 32];  // 64 KB

    const int tid = threadIdx.x;
    const int lane = tid & 63;
    const int w = tid >> 6;
    const int wm = w >> 2;
    const int wn = w & 3;
    const int r0 = lane & 15;
    const int rg = lane >> 4;

    const int srow = tid >> 2;
    const int gs = (tid & 3) ^ ((srow >> 1) & 3);
    const size_t offA = (size_t)(by * 128 + srow) * DK + gs * 8;
    const size_t offB = (size_t)(bx * 128 + srow) * DK + gs * 8;

    f32x4 acc[4][2];
#pragma unroll
    for (int m = 0; m < 4; ++m)
#pragma unroll
        for (int n = 0; n < 2; ++n) acc[m][n] = (f32x4){0.f, 0.f, 0.f, 0.f};

    int aoff[4], boff[2];
#pragma unroll
    for (int m = 0; m < 4; ++m) {
        const int row = wm * 64 + m * 16 + r0;
        aoff[m] = row * 32 + (rg ^ ((row >> 1) & 3)) * 8;
    }
#pragma unroll
    for (int n = 0; n < 2; ++n) {
        const int col = wn * 32 + n * 16 + r0;
        boff[n] = col * 32 + (rg ^ ((col >> 1) & 3)) * 8;
    }

    auto stage = [&](int kt) {
        const int buf = kt & 3;
        const size_t ko = (size_t)kt * 32;
        GLDS(A2h + offA + ko, &lA[buf][0][tid * 8]);
        GLDS(A2l + offA + ko, &lA[buf][1][tid * 8]);
        GLDS(Bh + offB + ko, &lB[buf][0][tid * 8]);
        GLDS(Bl + offB + ko, &lB[buf][1][tid * 8]);
    };

    stage(0); stage(1); stage(2);
    const int nK = DK / 32;
    for (int kt = 0; kt < nK; ++kt) {
        const int buf = kt & 3;
        if (kt + 3 < nK) {
            stage(kt + 3);
            asm volatile("s_waitcnt vmcnt(12)" ::: "memory");
        } else if (kt + 3 == nK) {
            asm volatile("s_waitcnt vmcnt(8)" ::: "memory");
        } else if (kt + 2 == nK) {
            asm volatile("s_waitcnt vmcnt(4)" ::: "memory");
        } else {
            asm volatile("s_waitcnt vmcnt(0)" ::: "memory");
        }
        __builtin_amdgcn_s_barrier();

        short8 bh[2], bl[2];
#pragma unroll
        for (int n = 0; n < 2; ++n) {
            bh[n] = *(const short8*)&lB[buf][0][boff[n]];
            bl[n] = *(const short8*)&lB[buf][1][boff[n]];
        }
#pragma unroll
        for (int m = 0; m < 4; ++m) {
            const short8 ah = *(const short8*)&lA[buf][0][aoff[m]];
            const short8 al = *(const short8*)&lA[buf][1][aoff[m]];
#pragma unroll
            for (int n = 0; n < 2; ++n) {
                acc[m][n] = __builtin_amdgcn_mfma_f32_16x16x32_bf16(ah, bh[n], acc[m][n], 0, 0, 0);
                acc[m][n] = __builtin_amdgcn_mfma_f32_16x16x32_bf16(ah, bl[n], acc[m][n], 0, 0, 0);
                acc[m][n] = __builtin_amdgcn_mfma_f32_16x16x32_bf16(al, bh[n], acc[m][n], 0, 0, 0);
            }
        }
        __builtin_amdgcn_s_barrier();
    }

#pragma unroll
    for (int m = 0; m < 4; ++m) {
#pragma unroll
        for (int j = 0; j < 4; ++j) {
            float best = acc[m][0][j];
            int bidx = bx * 128 + wn * 32 + r0;
            {
                const float v = acc[m][1][j];
                const int c = bx * 128 + wn * 32 + 16 + r0;
                if (v > best) { best = v; bidx = c; }
            }
#pragma unroll
            for (int off = 1; off < 16; off <<= 1) {
                const float ov = __shfl_xor(best, off, 64);
                const int oi = __shfl_xor(bidx, off, 64);
                if (ov > best || (ov == best && oi < bidx)) { best = ov; bidx = oi; }
            }
            const int slotg = by * 128 + wm * 64 + m * 16 + rg * 4 + j;
            if (r0 == 0 && slotg < cnt)
                cand2[(size_t)slotg * 32 + bx * 4 + wn] = make_float2(best, (float)bidx);
        }
    }
}

// ---------------- finalize pass 2 ----------------
__global__ void __launch_bounds__(256) finalizeB_kernel(const float2* __restrict__ cand2,
                                                        const int* __restrict__ wl,
                                                        const int* __restrict__ wc,
                                                        float* __restrict__ out) {
    const int slot = blockIdx.x * 256 + threadIdx.x;
    const int cnt = min(*wc, WLMAX);
    if (slot >= cnt) return;
    const int row = wl[slot];
    const float2* c = cand2 + (size_t)slot * 32;
    float best = c[0].x;
    float bi = c[0].y;
#pragma unroll
    for (int k = 1; k < 32; ++k) {
        const float2 p = c[k];
        if (p.x > best) { best = p.x; bi = p.y; }
    }
    out[row] = bi;
}

extern "C" void kernel_launch(void* const* d_in, const int* in_sizes, int n_in,
                              void* d_out, int out_size, void* d_ws, size_t ws_size,
                              hipStream_t stream) {
    const float* hvs = (const float*)d_in[0];  // [16384,4096] f32
    const float* am  = (const float*)d_in[1];  // [1024,4096] f32
    float* out = (float*)d_out;                // [preds | eta]

    ushort_t* Bh = (ushort_t*)d_ws;                      // 8 MB
    ushort_t* Bl = Bh + (size_t)NC * DK;                 // 8 MB
    ushort_t* Ah = Bl + (size_t)NC * DK;                 // 128 MB
    ushort_t* A2h = Ah + (size_t)NQ * DK;                // 64 MB
    ushort_t* A2l = A2h + (size_t)WLMAX * DK;            // 64 MB
    float4* cand = (float4*)(A2l + (size_t)WLMAX * DK);  // 4 MB
    float* s01 = (float*)(cand + (size_t)NQ * 16);       // 128 KB
    float2* cand2 = (float2*)(s01 + (size_t)NQ * 2);     // 4 MB
    int* wl = (int*)(cand2 + (size_t)WLMAX * 32);        // 32 KB
    int* wc = wl + WLMAX;                                // 4 B

    hipMemsetAsync(wc, 0, sizeof(int), stream);
    norm_all_kernel<<<NC + NQ, 256, 0, stream>>>(hvs, am, Ah, Bh, Bl);
    gemm1_kernel<<<512, 512, 0, stream>>>(Ah, Bh, cand, s01);
    finalizeA_kernel<<<NQ / 256, 256, 0, stream>>>(cand, s01, out, wl, wc);
    recheck_prep_kernel<<<WLMAX, 256, 0, stream>>>(hvs, wl, wc, A2h, A2l);
    gemm2_kernel<<<dim3(8, WLMAX / 128), 512, 0, stream>>>(A2h, A2l, Bh, Bl, wc, cand2);
    finalizeB_kernel<<<WLMAX / 256, 256, 0, stream>>>(cand2, wl, wc, out);
}

// Round 10
// 409.268 us; speedup vs baseline: 3.2257x; 3.2257x over previous
//
#include <hip/hip_runtime.h>
#include <hip/hip_bf16.h>

// N=16384 queries, C=1024 classes, D=4096.
// sims = l2norm(hvs) @ l2norm(am)^T ; preds = argmax ; eta = (sims[:,1]-sims[:,0])/4 + 0.5
// R10: gemm1 = m97-exact structure (128x128 tile, 256 thr, 4 waves, BK=32 dbuf,
// counted vmcnt(4), launch_bounds(256,3) -> 3-4 blocks/CU co-resident).
// R9's spill bug (launch_bounds(512,6) -> 40 VGPR) reverted. Rest = R8/R9 proven.

#define NQ 16384
#define NC 1024
#define DK 4096
#define TAU 4e-4f
#define WLMAX 8192

typedef __attribute__((ext_vector_type(8))) short short8;
typedef __attribute__((ext_vector_type(4))) float f32x4;
typedef unsigned short ushort_t;

__device__ __forceinline__ unsigned short bf16_rne(float x) {
    unsigned int u = __float_as_uint(x);
    u += 0x7FFFu + ((u >> 16) & 1u);
    return (unsigned short)(u >> 16);
}
__device__ __forceinline__ float bf16_f32(unsigned short h) {
    return __uint_as_float(((unsigned int)h) << 16);
}

#define GLDS(g, l)                                                                       \
    __builtin_amdgcn_global_load_lds((const __attribute__((address_space(1))) void*)(g), \
                                     (__attribute__((address_space(3))) void*)(l), 16, 0, 0)

// ---------------- fused row-norm + normalize + bf16 hi(/lo) split, both inputs ----------------
__global__ void __launch_bounds__(256) norm_all_kernel(const float* __restrict__ hvs,
                                                       const float* __restrict__ am,
                                                       ushort_t* __restrict__ Ah,
                                                       ushort_t* __restrict__ Bh,
                                                       ushort_t* __restrict__ Bl) {
    const int b = blockIdx.x;
    const int tid = threadIdx.x;
    const float* x;
    ushort_t *hp, *lp;
    bool wlo;
    if (b < NC) {
        x = am + (size_t)b * DK;
        hp = Bh + (size_t)b * DK;
        lp = Bl + (size_t)b * DK;
        wlo = true;
    } else {
        const int r = b - NC;
        x = hvs + (size_t)r * DK;
        hp = Ah + (size_t)r * DK;
        lp = nullptr;
        wlo = false;
    }
    const float4* x4 = (const float4*)x;

    float4 v[4];
    float ss = 0.f;
#pragma unroll
    for (int i = 0; i < 4; ++i) {
        v[i] = x4[tid * 4 + i];
        ss += v[i].x * v[i].x + v[i].y * v[i].y + v[i].z * v[i].z + v[i].w * v[i].w;
    }
#pragma unroll
    for (int off = 32; off; off >>= 1) ss += __shfl_xor(ss, off, 64);
    __shared__ float wsum[4];
    const int lane = tid & 63, w = tid >> 6;
    if (lane == 0) wsum[w] = ss;
    __syncthreads();
    const float tot = wsum[0] + wsum[1] + wsum[2] + wsum[3];
    const float r = 1.0f / fmaxf(sqrtf(tot), 1e-8f);

    ushort_t hbuf[16], lbuf[16];
#pragma unroll
    for (int i = 0; i < 4; ++i) {
        const float xs[4] = {v[i].x * r, v[i].y * r, v[i].z * r, v[i].w * r};
#pragma unroll
        for (int j = 0; j < 4; ++j) {
            const unsigned short h = bf16_rne(xs[j]);
            hbuf[i * 4 + j] = h;
            lbuf[i * 4 + j] = bf16_rne(xs[j] - bf16_f32(h));
        }
    }
    ushort_t* hq = hp + tid * 16;
    *(short8*)hq = *(short8*)hbuf;
    *(short8*)(hq + 8) = *(short8*)(hbuf + 8);
    if (wlo) {
        ushort_t* lq = lp + tid * 16;
        *(short8*)lq = *(short8*)lbuf;
        *(short8*)(lq + 8) = *(short8*)(lbuf + 8);
    }
}

// ---------------- pass 1: 1-term bf16 GEMM, m97 structure, fused top-2 ----------------
// 128x128 tile, 256 threads, 4 waves (2Mx2N, each 64x64), BK=32 dbuf (32 KB),
// issue-early GLDS + counted vmcnt(4), launch_bounds(256,3) -> co-resident.
__global__ void __launch_bounds__(256, 3) gemm1_kernel(const ushort_t* __restrict__ Ah,
                                                       const ushort_t* __restrict__ Bh,
                                                       float4* __restrict__ cand,
                                                       float* __restrict__ s01) {
    __shared__ __align__(16) ushort_t lA[2][128 * 32];  // 16 KB
    __shared__ __align__(16) ushort_t lB[2][128 * 32];  // 16 KB

    const int tid = threadIdx.x;
    const int lane = tid & 63;
    const int w = tid >> 6;   // 0..3
    const int wm = w >> 1;    // 0..1
    const int wn = w & 1;     // 0..1

    // XCD swizzle: each XCD owns 16 consecutive by-panels (x all 8 bx)
    const int id = blockIdx.x;              // 0..1023
    const int xcd = id & 7;
    const int slot = id >> 3;               // 0..127
    const int by = xcd * 16 + (slot >> 3);  // 0..127
    const int bx = slot & 7;                // 0..7

    // staging: per operand tile = 128 rows x 4 slots(16B) = 512 chunks; 2/thread
    int sq[2];
    size_t offA[2], offB[2];
#pragma unroll
    for (int i = 0; i < 2; ++i) {
        const int q = tid + i * 256;
        sq[i] = q;
        const int row = q >> 2;
        const int gs = (q & 3) ^ ((row >> 1) & 3);  // R3-proven swizzle
        offA[i] = (size_t)(by * 128 + row) * DK + gs * 8;
        offB[i] = (size_t)(bx * 128 + row) * DK + gs * 8;
    }

    f32x4 acc[4][4];
#pragma unroll
    for (int m = 0; m < 4; ++m)
#pragma unroll
        for (int n = 0; n < 4; ++n) acc[m][n] = (f32x4){0.f, 0.f, 0.f, 0.f};

    const int r0 = lane & 15;
    const int rg = lane >> 4;

    int aoff[4], boff[4];
#pragma unroll
    for (int m = 0; m < 4; ++m) {
        const int row = wm * 64 + m * 16 + r0;
        aoff[m] = row * 32 + (rg ^ ((row >> 1) & 3)) * 8;
    }
#pragma unroll
    for (int n = 0; n < 4; ++n) {
        const int col = wn * 64 + n * 16 + r0;
        boff[n] = col * 32 + (rg ^ ((col >> 1) & 3)) * 8;
    }

    auto stage = [&](int buf, int kt) {
        const size_t ko = (size_t)kt * 32;
        GLDS(Ah + offA[0] + ko, &lA[buf][sq[0] * 8]);
        GLDS(Ah + offA[1] + ko, &lA[buf][sq[1] * 8]);
        GLDS(Bh + offB[0] + ko, &lB[buf][sq[0] * 8]);
        GLDS(Bh + offB[1] + ko, &lB[buf][sq[1] * 8]);
    };

    stage(0, 0);
    const int nK = DK / 32;  // 128
    for (int kt = 0; kt < nK; ++kt) {
        const int cur = kt & 1;
        if (kt + 1 < nK) {
            stage(cur ^ 1, kt + 1);                           // 4 new loads in flight
            asm volatile("s_waitcnt vmcnt(4)" ::: "memory");  // cur's 4 done
        } else {
            asm volatile("s_waitcnt vmcnt(0)" ::: "memory");
        }
        __builtin_amdgcn_s_barrier();

        short8 b0 = *(const short8*)&lB[cur][boff[0]];
        short8 b1 = *(const short8*)&lB[cur][boff[1]];
        short8 b2 = *(const short8*)&lB[cur][boff[2]];
        short8 b3 = *(const short8*)&lB[cur][boff[3]];
        short8 a0 = *(const short8*)&lA[cur][aoff[0]];
        short8 a1 = *(const short8*)&lA[cur][aoff[1]];
        short8 a2 = *(const short8*)&lA[cur][aoff[2]];
        short8 a3 = *(const short8*)&lA[cur][aoff[3]];
        asm volatile("s_waitcnt lgkmcnt(0)" ::: "memory");
        __builtin_amdgcn_s_setprio(1);
        acc[0][0] = __builtin_amdgcn_mfma_f32_16x16x32_bf16(a0, b0, acc[0][0], 0, 0, 0);
        acc[0][1] = __builtin_amdgcn_mfma_f32_16x16x32_bf16(a0, b1, acc[0][1], 0, 0, 0);
        acc[0][2] = __builtin_amdgcn_mfma_f32_16x16x32_bf16(a0, b2, acc[0][2], 0, 0, 0);
        acc[0][3] = __builtin_amdgcn_mfma_f32_16x16x32_bf16(a0, b3, acc[0][3], 0, 0, 0);
        acc[1][0] = __builtin_amdgcn_mfma_f32_16x16x32_bf16(a1, b0, acc[1][0], 0, 0, 0);
        acc[1][1] = __builtin_amdgcn_mfma_f32_16x16x32_bf16(a1, b1, acc[1][1], 0, 0, 0);
        acc[1][2] = __builtin_amdgcn_mfma_f32_16x16x32_bf16(a1, b2, acc[1][2], 0, 0, 0);
        acc[1][3] = __builtin_amdgcn_mfma_f32_16x16x32_bf16(a1, b3, acc[1][3], 0, 0, 0);
        acc[2][0] = __builtin_amdgcn_mfma_f32_16x16x32_bf16(a2, b0, acc[2][0], 0, 0, 0);
        acc[2][1] = __builtin_amdgcn_mfma_f32_16x16x32_bf16(a2, b1, acc[2][1], 0, 0, 0);
        acc[2][2] = __builtin_amdgcn_mfma_f32_16x16x32_bf16(a2, b2, acc[2][2], 0, 0, 0);
        acc[2][3] = __builtin_amdgcn_mfma_f32_16x16x32_bf16(a2, b3, acc[2][3], 0, 0, 0);
        acc[3][0] = __builtin_amdgcn_mfma_f32_16x16x32_bf16(a3, b0, acc[3][0], 0, 0, 0);
        acc[3][1] = __builtin_amdgcn_mfma_f32_16x16x32_bf16(a3, b1, acc[3][1], 0, 0, 0);
        acc[3][2] = __builtin_amdgcn_mfma_f32_16x16x32_bf16(a3, b2, acc[3][2], 0, 0, 0);
        acc[3][3] = __builtin_amdgcn_mfma_f32_16x16x32_bf16(a3, b3, acc[3][3], 0, 0, 0);
        __builtin_amdgcn_s_setprio(0);
        __builtin_amdgcn_s_barrier();
    }

    // epilogue: C/D layout col=lane&15, row=(lane>>4)*4+j [m89]; per-strip top-2.
    // 16 col-strips of 64: strip = bx*2 + wn (ascending col order).
    const int rowb = by * 128 + wm * 64;
#pragma unroll
    for (int m = 0; m < 4; ++m) {
#pragma unroll
        for (int j = 0; j < 4; ++j) {
            float v1 = acc[m][0][j];
            int i1 = bx * 128 + wn * 64 + r0;
            float v2 = -3.402823466e+38f;
#pragma unroll
            for (int n = 1; n < 4; ++n) {
                const float v = acc[m][n][j];
                const int c = bx * 128 + wn * 64 + n * 16 + r0;
                if (v > v1) { v2 = v1; v1 = v; i1 = c; }
                else { v2 = fmaxf(v2, v); }
            }
#pragma unroll
            for (int off = 1; off < 16; off <<= 1) {
                const float o1 = __shfl_xor(v1, off, 64);
                const int oi = __shfl_xor(i1, off, 64);
                const float o2 = __shfl_xor(v2, off, 64);
                if (o1 > v1 || (o1 == v1 && oi < i1)) { v2 = fmaxf(v1, o2); v1 = o1; i1 = oi; }
                else { v2 = fmaxf(v2, o1); }
            }
            const int row = rowb + m * 16 + rg * 4 + j;
            if (r0 == 0)
                cand[(size_t)row * 16 + bx * 2 + wn] = make_float4(v1, (float)i1, v2, 0.f);
            if (bx == 0 && wn == 0 && r0 < 2) s01[row * 2 + r0] = acc[m][0][j];
        }
    }
}

// ---------------- finalize pass 1: merge strips, flag close rows ----------------
__global__ void __launch_bounds__(256) finalizeA_kernel(const float4* __restrict__ cand,
                                                        const float* __restrict__ s01,
                                                        float* __restrict__ out,
                                                        int* __restrict__ wl,
                                                        int* __restrict__ wc) {
    const int row = blockIdx.x * 256 + threadIdx.x;
    const float4* c = cand + (size_t)row * 16;
    float4 c0 = c[0];
    float M = c0.x, iM = c0.y, M2 = c0.z;
#pragma unroll
    for (int k = 1; k < 16; ++k) {
        const float4 ck = c[k];
        if (ck.x > M) { M2 = fmaxf(M, ck.z); M = ck.x; iM = ck.y; }
        else { M2 = fmaxf(M2, ck.x); }
    }
    out[row] = iM;
    out[NQ + row] = (s01[row * 2 + 1] - s01[row * 2 + 0]) * 0.25f + 0.5f;
    if (M - M2 < TAU) {
        const int p = atomicAdd(wc, 1);
        if (p < WLMAX) wl[p] = row;
    }
}

// ---------------- recheck prep: gather flagged rows, normalize + hi/lo split ----------------
__global__ void __launch_bounds__(256) recheck_prep_kernel(const float* __restrict__ hvs,
                                                           const int* __restrict__ wl,
                                                           const int* __restrict__ wc,
                                                           ushort_t* __restrict__ A2h,
                                                           ushort_t* __restrict__ A2l) {
    const int cnt = min(*wc, WLMAX);
    const int s = blockIdx.x;
    if (s >= cnt) return;
    const int row = wl[s];
    const int tid = threadIdx.x;
    const float4* x4 = (const float4*)(hvs + (size_t)row * DK);

    float4 v[4];
    float ss = 0.f;
#pragma unroll
    for (int i = 0; i < 4; ++i) {
        v[i] = x4[tid * 4 + i];
        ss += v[i].x * v[i].x + v[i].y * v[i].y + v[i].z * v[i].z + v[i].w * v[i].w;
    }
#pragma unroll
    for (int off = 32; off; off >>= 1) ss += __shfl_xor(ss, off, 64);
    __shared__ float wsum[4];
    const int lane = tid & 63, w = tid >> 6;
    if (lane == 0) wsum[w] = ss;
    __syncthreads();
    const float tot = wsum[0] + wsum[1] + wsum[2] + wsum[3];
    const float r = 1.0f / fmaxf(sqrtf(tot), 1e-8f);

    ushort_t hbuf[16], lbuf[16];
#pragma unroll
    for (int i = 0; i < 4; ++i) {
        const float xs[4] = {v[i].x * r, v[i].y * r, v[i].z * r, v[i].w * r};
#pragma unroll
        for (int j = 0; j < 4; ++j) {
            const unsigned short h = bf16_rne(xs[j]);
            hbuf[i * 4 + j] = h;
            lbuf[i * 4 + j] = bf16_rne(xs[j] - bf16_f32(h));
        }
    }
    ushort_t* hp = A2h + (size_t)s * DK + tid * 16;
    ushort_t* lp = A2l + (size_t)s * DK + tid * 16;
    *(short8*)hp = *(short8*)hbuf;
    *(short8*)(hp + 8) = *(short8*)(hbuf + 8);
    *(short8*)lp = *(short8*)lbuf;
    *(short8*)(lp + 8) = *(short8*)(lbuf + 8);
}

// ---------------- pass 2: 3-term recheck, 128x128 blocks, 4-deep ring ----------------
// (unchanged from R8)
__global__ void __launch_bounds__(512, 2) gemm2_kernel(const ushort_t* __restrict__ A2h,
                                                       const ushort_t* __restrict__ A2l,
                                                       const ushort_t* __restrict__ Bh,
                                                       const ushort_t* __restrict__ Bl,
                                                       const int* __restrict__ wc,
                                                       float2* __restrict__ cand2) {
    const int cnt = min(*wc, WLMAX);
    const int by = blockIdx.y;
    const int bx = blockIdx.x;
    if (by * 128 >= cnt) return;

    __shared__ __align__(16) ushort_t lA[4][2][128 * 32];  // 64 KB
    __shared__ __align__(16) ushort_t lB[4][2][128 * 32];  // 64 KB

    const int tid = threadIdx.x;
    const int lane = tid & 63;
    const int w = tid >> 6;
    const int wm = w >> 2;
    const int wn = w & 3;
    const int r0 = lane & 15;
    const int rg = lane >> 4;

    const int srow = tid >> 2;
    const int gs = (tid & 3) ^ ((srow >> 1) & 3);
    const size_t offA = (size_t)(by * 128 + srow) * DK + gs * 8;
    const size_t offB = (size_t)(bx * 128 + srow) * DK + gs * 8;

    f32x4 acc[4][2];
#pragma unroll
    for (int m = 0; m < 4; ++m)
#pragma unroll
        for (int n = 0; n < 2; ++n) acc[m][n] = (f32x4){0.f, 0.f, 0.f, 0.f};

    int aoff[4], boff[2];
#pragma unroll
    for (int m = 0; m < 4; ++m) {
        const int row = wm * 64 + m * 16 + r0;
        aoff[m] = row * 32 + (rg ^ ((row >> 1) & 3)) * 8;
    }
#pragma unroll
    for (int n = 0; n < 2; ++n) {
        const int col = wn * 32 + n * 16 + r0;
        boff[n] = col * 32 + (rg ^ ((col >> 1) & 3)) * 8;
    }

    auto stage = [&](int kt) {
        const int buf = kt & 3;
        const size_t ko = (size_t)kt * 32;
        GLDS(A2h + offA + ko, &lA[buf][0][tid * 8]);
        GLDS(A2l + offA + ko, &lA[buf][1][tid * 8]);
        GLDS(Bh + offB + ko, &lB[buf][0][tid * 8]);
        GLDS(Bl + offB + ko, &lB[buf][1][tid * 8]);
    };

    stage(0); stage(1); stage(2);
    const int nK = DK / 32;
    for (int kt = 0; kt < nK; ++kt) {
        const int buf = kt & 3;
        if (kt + 3 < nK) {
            stage(kt + 3);
            asm volatile("s_waitcnt vmcnt(12)" ::: "memory");
        } else if (kt + 3 == nK) {
            asm volatile("s_waitcnt vmcnt(8)" ::: "memory");
        } else if (kt + 2 == nK) {
            asm volatile("s_waitcnt vmcnt(4)" ::: "memory");
        } else {
            asm volatile("s_waitcnt vmcnt(0)" ::: "memory");
        }
        __builtin_amdgcn_s_barrier();

        short8 bh[2], bl[2];
#pragma unroll
        for (int n = 0; n < 2; ++n) {
            bh[n] = *(const short8*)&lB[buf][0][boff[n]];
            bl[n] = *(const short8*)&lB[buf][1][boff[n]];
        }
#pragma unroll
        for (int m = 0; m < 4; ++m) {
            const short8 ah = *(const short8*)&lA[buf][0][aoff[m]];
            const short8 al = *(const short8*)&lA[buf][1][aoff[m]];
#pragma unroll
            for (int n = 0; n < 2; ++n) {
                acc[m][n] = __builtin_amdgcn_mfma_f32_16x16x32_bf16(ah, bh[n], acc[m][n], 0, 0, 0);
                acc[m][n] = __builtin_amdgcn_mfma_f32_16x16x32_bf16(ah, bl[n], acc[m][n], 0, 0, 0);
                acc[m][n] = __builtin_amdgcn_mfma_f32_16x16x32_bf16(al, bh[n], acc[m][n], 0, 0, 0);
            }
        }
        __builtin_amdgcn_s_barrier();
    }

#pragma unroll
    for (int m = 0; m < 4; ++m) {
#pragma unroll
        for (int j = 0; j < 4; ++j) {
            float best = acc[m][0][j];
            int bidx = bx * 128 + wn * 32 + r0;
            {
                const float v = acc[m][1][j];
                const int c = bx * 128 + wn * 32 + 16 + r0;
                if (v > best) { best = v; bidx = c; }
            }
#pragma unroll
            for (int off = 1; off < 16; off <<= 1) {
                const float ov = __shfl_xor(best, off, 64);
                const int oi = __shfl_xor(bidx, off, 64);
                if (ov > best || (ov == best && oi < bidx)) { best = ov; bidx = oi; }
            }
            const int slotg = by * 128 + wm * 64 + m * 16 + rg * 4 + j;
            if (r0 == 0 && slotg < cnt)
                cand2[(size_t)slotg * 32 + bx * 4 + wn] = make_float2(best, (float)bidx);
        }
    }
}

// ---------------- finalize pass 2 ----------------
__global__ void __launch_bounds__(256) finalizeB_kernel(const float2* __restrict__ cand2,
                                                        const int* __restrict__ wl,
                                                        const int* __restrict__ wc,
                                                        float* __restrict__ out) {
    const int slot = blockIdx.x * 256 + threadIdx.x;
    const int cnt = min(*wc, WLMAX);
    if (slot >= cnt) return;
    const int row = wl[slot];
    const float2* c = cand2 + (size_t)slot * 32;
    float best = c[0].x;
    float bi = c[0].y;
#pragma unroll
    for (int k = 1; k < 32; ++k) {
        const float2 p = c[k];
        if (p.x > best) { best = p.x; bi = p.y; }
    }
    out[row] = bi;
}

extern "C" void kernel_launch(void* const* d_in, const int* in_sizes, int n_in,
                              void* d_out, int out_size, void* d_ws, size_t ws_size,
                              hipStream_t stream) {
    const float* hvs = (const float*)d_in[0];  // [16384,4096] f32
    const float* am  = (const float*)d_in[1];  // [1024,4096] f32
    float* out = (float*)d_out;                // [preds | eta]

    ushort_t* Bh = (ushort_t*)d_ws;                      // 8 MB
    ushort_t* Bl = Bh + (size_t)NC * DK;                 // 8 MB
    ushort_t* Ah = Bl + (size_t)NC * DK;                 // 128 MB
    ushort_t* A2h = Ah + (size_t)NQ * DK;                // 64 MB
    ushort_t* A2l = A2h + (size_t)WLMAX * DK;            // 64 MB
    float4* cand = (float4*)(A2l + (size_t)WLMAX * DK);  // 4 MB
    float* s01 = (float*)(cand + (size_t)NQ * 16);       // 128 KB
    float2* cand2 = (float2*)(s01 + (size_t)NQ * 2);     // 4 MB
    int* wl = (int*)(cand2 + (size_t)WLMAX * 32);        // 32 KB
    int* wc = wl + WLMAX;                                // 4 B

    hipMemsetAsync(wc, 0, sizeof(int), stream);
    norm_all_kernel<<<NC + NQ, 256, 0, stream>>>(hvs, am, Ah, Bh, Bl);
    gemm1_kernel<<<1024, 256, 0, stream>>>(Ah, Bh, cand, s01);
    finalizeA_kernel<<<NQ / 256, 256, 0, stream>>>(cand, s01, out, wl, wc);
    recheck_prep_kernel<<<WLMAX, 256, 0, stream>>>(hvs, wl, wc, A2h, A2l);
    gemm2_kernel<<<dim3(8, WLMAX / 128), 512, 0, stream>>>(A2h, A2l, Bh, Bl, wc, cand2);
    finalizeB_kernel<<<WLMAX / 256, 256, 0, stream>>>(cand2, wl, wc, out);
}